// Round 12
// baseline (215.967 us; speedup 1.0000x reference)
//
#include <hip/hip_runtime.h>
#include <math.h>

#define FFT_N 16384
#define NT 512
#define B_DIM 8
#define H_DIM 256

// Per-wave LDS region, pad 1 float per 32 (R2-proven scheme).
#define REGION 2048
#define RW (REGION + (REGION >> 5))      // 2112 floats per region per plane
#define PAD(x) ((x) + ((x) >> 5))

// Intra-wave LDS fence (verified R7+).
#define WAVE_LDS_FENCE() do {                                   \
    __builtin_amdgcn_sched_barrier(0);                          \
    asm volatile("s_waitcnt lgkmcnt(0)" ::: "memory");          \
    __builtin_amdgcn_sched_barrier(0);                          \
} while (0)

__device__ __forceinline__ float2 cmul(float2 a, float2 b) {
    return make_float2(a.x * b.x - a.y * b.y, a.x * b.y + a.y * b.x);
}
__device__ __forceinline__ float2 cadd(float2 a, float2 b) { return make_float2(a.x + b.x, a.y + b.y); }
__device__ __forceinline__ float2 csub(float2 a, float2 b) { return make_float2(a.x - b.x, a.y - b.y); }
__device__ __forceinline__ float2 mulnegi(float2 z) { return make_float2(z.y, -z.x); }   // -i*z
__device__ __forceinline__ float2 mulposi(float2 z) { return make_float2(-z.y, z.x); }   // +i*z

// ---- radix-4 butterflies (verified R1..R11) ----
__device__ __forceinline__ void bfly4(float2& a, float2& b, float2& c, float2& d,
                                      float2 w1, float2 w2, float2 w3) {
    float2 apc = cadd(a, c), amc = csub(a, c);
    float2 bpd = cadd(b, d), bmd = csub(b, d);
    float2 nib = mulnegi(bmd);
    a = cadd(apc, bpd);
    b = cmul(csub(apc, bpd), w2);
    c = cmul(cadd(amc, nib), w1);
    d = cmul(csub(amc, nib), w3);
}
__device__ __forceinline__ void bfly4_nw(float2& a, float2& b, float2& c, float2& d) {
    float2 apc = cadd(a, c), amc = csub(a, c);
    float2 bpd = cadd(b, d), bmd = csub(b, d);
    float2 nib = mulnegi(bmd);
    a = cadd(apc, bpd);
    b = csub(apc, bpd);
    c = cadd(amc, nib);
    d = csub(amc, nib);
}
__device__ __forceinline__ void ibfly4(float2& a, float2& b, float2& c, float2& d,
                                       float2 w1t, float2 w2t) {
    float2 w1 = make_float2(w1t.x, -w1t.y);
    float2 w2 = make_float2(w2t.x, -w2t.y);
    float2 bt = cmul(b, w2), dt = cmul(d, w2);
    float2 A = cadd(a, bt), Bb = csub(a, bt);
    float2 C = cadd(c, dt), Dd = csub(c, dt);
    float2 Cw = cmul(C, w1);
    float2 Dw = mulposi(cmul(Dd, w1));
    a = cadd(A, Cw);  c = csub(A, Cw);
    b = cadd(Bb, Dw); d = csub(Bb, Dw);
}
__device__ __forceinline__ void ibfly4_nw(float2& a, float2& b, float2& c, float2& d) {
    float2 A = cadd(a, b), Bb = csub(a, b);
    float2 C = cadd(c, d), Dd = csub(c, d);
    float2 Dw = mulposi(Dd);
    a = cadd(A, C);  c = csub(A, C);
    b = cadd(Bb, Dw); d = csub(Bb, Dw);
}

// ---- g01 half-passes (verified R10/R11) ----
__device__ __forceinline__ void fwd_g01_half(float2 rh[16], const int t, const int par,
                                             const float2* __restrict__ tw) {
#pragma unroll
    for (int m0 = 0; m0 < 4; ++m0) {
        const int i = t + 512 * par + 1024 * m0;
        bfly4(rh[m0], rh[m0 + 4], rh[m0 + 8], rh[m0 + 12], tw[i], tw[2 * i], tw[3 * i]);
    }
    {
        const int ig = (t + 512 * par) * 4;
        const float2 w1 = tw[ig], w2 = tw[2 * ig], w3 = tw[3 * ig];
#pragma unroll
        for (int a = 0; a < 4; ++a)
            bfly4(rh[4 * a], rh[4 * a + 1], rh[4 * a + 2], rh[4 * a + 3], w1, w2, w3);
    }
}
__device__ __forceinline__ void inv_g01_half(float2 rh[16], const int t, const int par,
                                             const float2* __restrict__ tw) {
    {
        const int ig = (t + 512 * par) * 4;
        const float2 w1 = tw[ig], w2 = tw[2 * ig];
#pragma unroll
        for (int a = 0; a < 4; ++a)
            ibfly4(rh[4 * a], rh[4 * a + 1], rh[4 * a + 2], rh[4 * a + 3], w1, w2);
    }
#pragma unroll
    for (int m0 = 0; m0 < 4; ++m0) {
        const int i = t + 512 * par + 1024 * m0;
        ibfly4(rh[m0], rh[m0 + 4], rh[m0 + 8], rh[m0 + 12], tw[i], tw[2 * i]);
    }
}

// ---- per-s mid half (kfft only; verified R10) ----
__device__ __forceinline__ void fwd_mid_half(float2 rh[16], float* ldsx, float* ldsy,
                                             const int w, const int l, const int s,
                                             const float2* __restrict__ tw) {
#pragma unroll
    for (int jj = 0; jj < 16; ++jj) {
        const int a = w * RW + PAD(1024 * s + 64 * jj + l);
        rh[jj].x = ldsx[a]; rh[jj].y = ldsy[a];
    }
#pragma unroll
    for (int j0 = 0; j0 < 4; ++j0) {
        const int i1 = 1024 * j0 + 16 * l;
        bfly4(rh[j0], rh[j0 + 4], rh[j0 + 8], rh[j0 + 12], tw[i1], tw[2 * i1], tw[3 * i1]);
    }
    {
        const int i2 = 64 * l;
        const float2 w1 = tw[i2], w2 = tw[2 * i2], w3 = tw[3 * i2];
#pragma unroll
        for (int g = 0; g < 4; ++g)
            bfly4(rh[4 * g], rh[4 * g + 1], rh[4 * g + 2], rh[4 * g + 3], w1, w2, w3);
    }
#pragma unroll
    for (int jj = 0; jj < 16; ++jj) {
        const int a = w * RW + PAD(1024 * s + 64 * jj + l);
        ldsx[a] = rh[jj].x; ldsy[a] = rh[jj].y;
    }
    WAVE_LDS_FENCE();
    {
        const int lo = 64 * (l >> 2) + (l & 3);
#pragma unroll
        for (int jj = 0; jj < 16; ++jj) {
            const int a = w * RW + PAD(1024 * s + lo + 4 * jj);
            rh[jj].x = ldsx[a]; rh[jj].y = ldsy[a];
        }
    }
#pragma unroll
    for (int j0 = 0; j0 < 4; ++j0) {
        const int i3 = 1024 * j0 + 256 * (l & 3);
        bfly4(rh[j0], rh[j0 + 4], rh[j0 + 8], rh[j0 + 12], tw[i3], tw[2 * i3], tw[3 * i3]);
    }
    {
        const int i4 = 1024 * (l & 3);
        const float2 w1 = tw[i4], w2 = tw[2 * i4], w3 = tw[3 * i4];
#pragma unroll
        for (int g = 0; g < 4; ++g)
            bfly4(rh[4 * g], rh[4 * g + 1], rh[4 * g + 2], rh[4 * g + 3], w1, w2, w3);
    }
    {
        const int lo = 64 * (l >> 2) + (l & 3);
#pragma unroll
        for (int jj = 0; jj < 16; ++jj) {
            const int a = w * RW + PAD(1024 * s + lo + 4 * jj);
            ldsx[a] = rh[jj].x; ldsy[a] = rh[jj].y;
        }
    }
    WAVE_LDS_FENCE();
#pragma unroll
    for (int jj = 0; jj < 16; ++jj) {
        const int a = w * RW + PAD(1024 * s + 16 * l + jj);
        rh[jj].x = ldsx[a]; rh[jj].y = ldsy[a];
    }
#pragma unroll
    for (int g = 0; g < 4; ++g)
        bfly4_nw(rh[4 * g], rh[4 * g + 1], rh[4 * g + 2], rh[4 * g + 3]);
}

__device__ __forceinline__ float ftanh(float x) {
    float e = __expf(2.0f * x);
    return 1.0f - 2.0f * __builtin_amdgcn_rcpf(e + 1.0f);
}

__global__ void twiddle_init(float2* __restrict__ tw) {
    int t = blockIdx.x * blockDim.x + threadIdx.x;
    if (t < FFT_N) {
        float ang = -2.0f * 3.14159265358979323846f * (float)t / (float)FFT_N;
        float sv, cv;
        sincosf(ang, &sv, &cv);
        tw[t] = make_float2(cv, sv);
    }
}

// Forward FFT of (k_h + dh*delta) -> Kf[h], thread-linear W3 order, PRE-SCALED
// by 1/N (the pointwise scale folded here once; conv multiplies z*Kf only).
__global__ __launch_bounds__(NT) void kfft_kernel(const float* __restrict__ k,
                                                  const float* __restrict__ D,
                                                  const float2* __restrict__ tw,
                                                  float2* __restrict__ Kf) {
    __shared__ float ldsx[8 * RW];
    __shared__ float ldsy[8 * RW];
    const int h = blockIdx.x;
    const int t = threadIdx.x;
    const int w = t >> 6, l = t & 63;
    const float* krow = k + (size_t)h * FFT_N;
    const float dh = D[h * (H_DIM + 1)];
#pragma unroll
    for (int par = 0; par < 2; ++par) {
        float2 rh[16];
#pragma unroll
        for (int m = 0; m < 16; ++m)
            rh[m] = make_float2(krow[t + 512 * par + 1024 * m], 0.f);
        if (par == 0 && t == 0) rh[0].x += dh;   // fold diag(D) into k's 0th tap
        fwd_g01_half(rh, t, par, tw);
#pragma unroll
        for (int m = 0; m < 16; ++m) {
            const int e = t + 512 * par + 1024 * m;
            const int a = (e >> 11) * RW + PAD(e & 2047);
            ldsx[a] = rh[m].x; ldsy[a] = rh[m].y;
        }
    }
    __syncthreads();
    const float invN = 1.0f / (float)FFT_N;
    float4* out4 = (float4*)(Kf + (size_t)h * FFT_N);
#pragma unroll
    for (int s = 0; s < 2; ++s) {
        float2 rh[16];
        fwd_mid_half(rh, ldsx, ldsy, w, l, s, tw);
#pragma unroll
        for (int q = 0; q < 8; ++q)
            out4[16 * t + 8 * s + q] =
                make_float4(rh[2 * q].x * invN, rh[2 * q].y * invN,
                            rh[2 * q + 1].x * invN, rh[2 * q + 1].y * invN);
    }
}

// Batch rows (2p,h) and (2p+1,h) packed as z = u0 + i*u1.
// Middle = 5 phases, each "for s: {read, bfly, write}" with ONE shared fence
// between phases: R11's 4-fence count at R10's 16-float2 liveness (no spill).
__global__ __launch_bounds__(NT) void conv_kernel(const float* __restrict__ u,
                                                  const float2* __restrict__ tw,
                                                  const float2* __restrict__ Kf,
                                                  float* __restrict__ out) {
    __shared__ float ldsx[8 * RW];
    __shared__ float ldsy[8 * RW];
    const int raw = blockIdx.x;
    const int vb = ((raw & 7) << 7) + (raw >> 3);   // XCD-chunked bijection
    const int h = vb >> 2;
    const int p = vb & 3;
    const int t = threadIdx.x;
    const int w = t >> 6, l = t & 63;
    const size_t row0 = ((size_t)(2 * p) * H_DIM + h) * FFT_N;
    const size_t row1 = row0 + (size_t)H_DIM * FFT_N;
    const float* u0 = u + row0;
    const float* u1 = u + row1;

    // entry: two independent 16-register half-passes (spill-free, verified R10/R11)
#pragma unroll
    for (int par = 0; par < 2; ++par) {
        float2 rh[16];
#pragma unroll
        for (int m = 0; m < 16; ++m) {
            const int n = t + 512 * par + 1024 * m;
            rh[m] = make_float2(u0[n], u1[n]);
        }
        fwd_g01_half(rh, t, par, tw);
#pragma unroll
        for (int m = 0; m < 16; ++m) {
            const int e = t + 512 * par + 1024 * m;
            const int a = (e >> 11) * RW + PAD(e & 2047);
            ldsx[a] = rh[m].x; ldsy[a] = rh[m].y;
        }
    }
    __syncthreads();

    const float4* kf4 = (const float4*)(Kf + (size_t)h * FFT_N);
    const int lo = 64 * (l >> 2) + (l & 3);

    // Phase A: fwd q=256, q=64 (W1 slots in/out)
#pragma unroll
    for (int s = 0; s < 2; ++s) {
        float2 rh[16];
#pragma unroll
        for (int jj = 0; jj < 16; ++jj) {
            const int a = w * RW + PAD(1024 * s + 64 * jj + l);
            rh[jj].x = ldsx[a]; rh[jj].y = ldsy[a];
        }
#pragma unroll
        for (int j0 = 0; j0 < 4; ++j0) {
            const int i1 = 1024 * j0 + 16 * l;
            bfly4(rh[j0], rh[j0 + 4], rh[j0 + 8], rh[j0 + 12], tw[i1], tw[2 * i1], tw[3 * i1]);
        }
        {
            const int i2 = 64 * l;
            const float2 w1 = tw[i2], w2 = tw[2 * i2], w3 = tw[3 * i2];
#pragma unroll
            for (int g = 0; g < 4; ++g)
                bfly4(rh[4 * g], rh[4 * g + 1], rh[4 * g + 2], rh[4 * g + 3], w1, w2, w3);
        }
#pragma unroll
        for (int jj = 0; jj < 16; ++jj) {
            const int a = w * RW + PAD(1024 * s + 64 * jj + l);
            ldsx[a] = rh[jj].x; ldsy[a] = rh[jj].y;
        }
    }
    WAVE_LDS_FENCE();

    // Phase B: fwd q=16, q=4 (W2 slots in/out)
#pragma unroll
    for (int s = 0; s < 2; ++s) {
        float2 rh[16];
#pragma unroll
        for (int jj = 0; jj < 16; ++jj) {
            const int a = w * RW + PAD(1024 * s + lo + 4 * jj);
            rh[jj].x = ldsx[a]; rh[jj].y = ldsy[a];
        }
#pragma unroll
        for (int j0 = 0; j0 < 4; ++j0) {
            const int i3 = 1024 * j0 + 256 * (l & 3);
            bfly4(rh[j0], rh[j0 + 4], rh[j0 + 8], rh[j0 + 12], tw[i3], tw[2 * i3], tw[3 * i3]);
        }
        {
            const int i4 = 1024 * (l & 3);
            const float2 w1 = tw[i4], w2 = tw[2 * i4], w3 = tw[3 * i4];
#pragma unroll
            for (int g = 0; g < 4; ++g)
                bfly4(rh[4 * g], rh[4 * g + 1], rh[4 * g + 2], rh[4 * g + 3], w1, w2, w3);
        }
#pragma unroll
        for (int jj = 0; jj < 16; ++jj) {
            const int a = w * RW + PAD(1024 * s + lo + 4 * jj);
            ldsx[a] = rh[jj].x; ldsy[a] = rh[jj].y;
        }
    }
    WAVE_LDS_FENCE();

    // Phase C: fwd q=1, pointwise (Kf pre-scaled by 1/N), inv q=1 (W3 slots in/out)
#pragma unroll
    for (int s = 0; s < 2; ++s) {
        float4 kq[8];
#pragma unroll
        for (int q = 0; q < 8; ++q) kq[q] = kf4[16 * t + 8 * s + q];
        float2 rh[16];
#pragma unroll
        for (int jj = 0; jj < 16; ++jj) {
            const int a = w * RW + PAD(1024 * s + 16 * l + jj);
            rh[jj].x = ldsx[a]; rh[jj].y = ldsy[a];
        }
#pragma unroll
        for (int g = 0; g < 4; ++g)
            bfly4_nw(rh[4 * g], rh[4 * g + 1], rh[4 * g + 2], rh[4 * g + 3]);
#pragma unroll
        for (int q = 0; q < 8; ++q) {
            float2 z;
            z = rh[2 * q];
            rh[2 * q]     = make_float2(z.x * kq[q].x - z.y * kq[q].y,
                                        z.x * kq[q].y + z.y * kq[q].x);
            z = rh[2 * q + 1];
            rh[2 * q + 1] = make_float2(z.x * kq[q].z - z.y * kq[q].w,
                                        z.x * kq[q].w + z.y * kq[q].z);
        }
#pragma unroll
        for (int g = 0; g < 4; ++g)
            ibfly4_nw(rh[4 * g], rh[4 * g + 1], rh[4 * g + 2], rh[4 * g + 3]);
#pragma unroll
        for (int jj = 0; jj < 16; ++jj) {
            const int a = w * RW + PAD(1024 * s + 16 * l + jj);
            ldsx[a] = rh[jj].x; ldsy[a] = rh[jj].y;
        }
    }
    WAVE_LDS_FENCE();

    // Phase D: inv q=4, q=16 (W2 slots in/out)
#pragma unroll
    for (int s = 0; s < 2; ++s) {
        float2 rh[16];
#pragma unroll
        for (int jj = 0; jj < 16; ++jj) {
            const int a = w * RW + PAD(1024 * s + lo + 4 * jj);
            rh[jj].x = ldsx[a]; rh[jj].y = ldsy[a];
        }
        {
            const int i4 = 1024 * (l & 3);
            const float2 w1 = tw[i4], w2 = tw[2 * i4];
#pragma unroll
            for (int g = 0; g < 4; ++g)
                ibfly4(rh[4 * g], rh[4 * g + 1], rh[4 * g + 2], rh[4 * g + 3], w1, w2);
        }
#pragma unroll
        for (int j0 = 0; j0 < 4; ++j0) {
            const int i3 = 1024 * j0 + 256 * (l & 3);
            ibfly4(rh[j0], rh[j0 + 4], rh[j0 + 8], rh[j0 + 12], tw[i3], tw[2 * i3]);
        }
#pragma unroll
        for (int jj = 0; jj < 16; ++jj) {
            const int a = w * RW + PAD(1024 * s + lo + 4 * jj);
            ldsx[a] = rh[jj].x; ldsy[a] = rh[jj].y;
        }
    }
    WAVE_LDS_FENCE();

    // Phase E: inv q=64, q=256 (W1 slots in/out)
#pragma unroll
    for (int s = 0; s < 2; ++s) {
        float2 rh[16];
#pragma unroll
        for (int jj = 0; jj < 16; ++jj) {
            const int a = w * RW + PAD(1024 * s + 64 * jj + l);
            rh[jj].x = ldsx[a]; rh[jj].y = ldsy[a];
        }
        {
            const int i2 = 64 * l;
            const float2 w1 = tw[i2], w2 = tw[2 * i2];
#pragma unroll
            for (int g = 0; g < 4; ++g)
                ibfly4(rh[4 * g], rh[4 * g + 1], rh[4 * g + 2], rh[4 * g + 3], w1, w2);
        }
#pragma unroll
        for (int j0 = 0; j0 < 4; ++j0) {
            const int i1 = 1024 * j0 + 16 * l;
            ibfly4(rh[j0], rh[j0 + 4], rh[j0 + 8], rh[j0 + 12], tw[i1], tw[2 * i1]);
        }
#pragma unroll
        for (int jj = 0; jj < 16; ++jj) {
            const int a = w * RW + PAD(1024 * s + 64 * jj + l);
            ldsx[a] = rh[jj].x; ldsy[a] = rh[jj].y;
        }
    }
    __syncthreads();

    // exit: per-parity half-passes
    float* o0 = out + row0;
    float* o1 = out + row1;
#pragma unroll
    for (int par = 0; par < 2; ++par) {
        float2 rh[16];
#pragma unroll
        for (int m = 0; m < 16; ++m) {
            const int e = t + 512 * par + 1024 * m;
            const int a = (e >> 11) * RW + PAD(e & 2047);
            rh[m].x = ldsx[a]; rh[m].y = ldsy[a];
        }
        inv_g01_half(rh, t, par, tw);
#pragma unroll
        for (int m = 0; m < 16; ++m) {
            const int n = t + 512 * par + 1024 * m;
            o0[n] = ftanh(rh[m].x);
            o1[n] = ftanh(rh[m].y);
        }
    }
}

extern "C" void kernel_launch(void* const* d_in, const int* in_sizes, int n_in,
                              void* d_out, int out_size, void* d_ws, size_t ws_size,
                              hipStream_t stream) {
    const float* u = (const float*)d_in[0];   // (B,H,L) f32
    const float* k = (const float*)d_in[1];   // (H,L)   f32
    const float* D = (const float*)d_in[2];   // (H,H)   f32
    float* out = (float*)d_out;

    float2* tw = (float2*)d_ws;               // 16384 float2 = 128 KiB
    float2* Kf = tw + FFT_N;                  // 256*16384 float2 = 32 MiB

    twiddle_init<<<FFT_N / 256, 256, 0, stream>>>(tw);
    kfft_kernel<<<H_DIM, NT, 0, stream>>>(k, D, tw, Kf);
    conv_kernel<<<(B_DIM / 2) * H_DIM, NT, 0, stream>>>(u, tw, Kf, out);
}

// Round 13
// 209.759 us; speedup vs baseline: 1.0296x; 1.0296x over previous
//
#include <hip/hip_runtime.h>
#include <math.h>

#define FFT_N 16384
#define NT 512
#define B_DIM 8
#define H_DIM 256

// Per-wave LDS region, pad 1 float per 32 (R2-proven scheme).
#define REGION 2048
#define RW (REGION + (REGION >> 5))      // 2112 floats per region per plane
#define PAD(x) ((x) + ((x) >> 5))

// NOTE (R13): no explicit wave-local fences. DS ops of one wave complete in
// order on CDNA, and the compiler preserves program order for may-aliasing
// LDS accesses and inserts counted lgkmcnt waits before consumers. The old
// full-drain fence serialized each exchange; removing it lets reads pipeline
// under the write tail. Cross-wave exchanges still use __syncthreads.

__device__ __forceinline__ float2 cmul(float2 a, float2 b) {
    return make_float2(a.x * b.x - a.y * b.y, a.x * b.y + a.y * b.x);
}
__device__ __forceinline__ float2 cadd(float2 a, float2 b) { return make_float2(a.x + b.x, a.y + b.y); }
__device__ __forceinline__ float2 csub(float2 a, float2 b) { return make_float2(a.x - b.x, a.y - b.y); }
__device__ __forceinline__ float2 mulnegi(float2 z) { return make_float2(z.y, -z.x); }   // -i*z
__device__ __forceinline__ float2 mulposi(float2 z) { return make_float2(-z.y, z.x); }   // +i*z

// ---- radix-4 butterflies (verified R1..R12) ----
__device__ __forceinline__ void bfly4(float2& a, float2& b, float2& c, float2& d,
                                      float2 w1, float2 w2, float2 w3) {
    float2 apc = cadd(a, c), amc = csub(a, c);
    float2 bpd = cadd(b, d), bmd = csub(b, d);
    float2 nib = mulnegi(bmd);
    a = cadd(apc, bpd);
    b = cmul(csub(apc, bpd), w2);
    c = cmul(cadd(amc, nib), w1);
    d = cmul(csub(amc, nib), w3);
}
__device__ __forceinline__ void bfly4_nw(float2& a, float2& b, float2& c, float2& d) {
    float2 apc = cadd(a, c), amc = csub(a, c);
    float2 bpd = cadd(b, d), bmd = csub(b, d);
    float2 nib = mulnegi(bmd);
    a = cadd(apc, bpd);
    b = csub(apc, bpd);
    c = cadd(amc, nib);
    d = csub(amc, nib);
}
__device__ __forceinline__ void ibfly4(float2& a, float2& b, float2& c, float2& d,
                                       float2 w1t, float2 w2t) {
    float2 w1 = make_float2(w1t.x, -w1t.y);
    float2 w2 = make_float2(w2t.x, -w2t.y);
    float2 bt = cmul(b, w2), dt = cmul(d, w2);
    float2 A = cadd(a, bt), Bb = csub(a, bt);
    float2 C = cadd(c, dt), Dd = csub(c, dt);
    float2 Cw = cmul(C, w1);
    float2 Dw = mulposi(cmul(Dd, w1));
    a = cadd(A, Cw);  c = csub(A, Cw);
    b = cadd(Bb, Dw); d = csub(Bb, Dw);
}
__device__ __forceinline__ void ibfly4_nw(float2& a, float2& b, float2& c, float2& d) {
    float2 A = cadd(a, b), Bb = csub(a, b);
    float2 C = cadd(c, d), Dd = csub(c, d);
    float2 Dw = mulposi(Dd);
    a = cadd(A, C);  c = csub(A, C);
    b = cadd(Bb, Dw); d = csub(Bb, Dw);
}

// ---- g01 half-passes (verified R10..R12) ----
__device__ __forceinline__ void fwd_g01_half(float2 rh[16], const int t, const int par,
                                             const float2* __restrict__ tw) {
#pragma unroll
    for (int m0 = 0; m0 < 4; ++m0) {
        const int i = t + 512 * par + 1024 * m0;
        bfly4(rh[m0], rh[m0 + 4], rh[m0 + 8], rh[m0 + 12], tw[i], tw[2 * i], tw[3 * i]);
    }
    {
        const int ig = (t + 512 * par) * 4;
        const float2 w1 = tw[ig], w2 = tw[2 * ig], w3 = tw[3 * ig];
#pragma unroll
        for (int a = 0; a < 4; ++a)
            bfly4(rh[4 * a], rh[4 * a + 1], rh[4 * a + 2], rh[4 * a + 3], w1, w2, w3);
    }
}
__device__ __forceinline__ void inv_g01_half(float2 rh[16], const int t, const int par,
                                             const float2* __restrict__ tw) {
    {
        const int ig = (t + 512 * par) * 4;
        const float2 w1 = tw[ig], w2 = tw[2 * ig];
#pragma unroll
        for (int a = 0; a < 4; ++a)
            ibfly4(rh[4 * a], rh[4 * a + 1], rh[4 * a + 2], rh[4 * a + 3], w1, w2);
    }
#pragma unroll
    for (int m0 = 0; m0 < 4; ++m0) {
        const int i = t + 512 * par + 1024 * m0;
        ibfly4(rh[m0], rh[m0 + 4], rh[m0 + 8], rh[m0 + 12], tw[i], tw[2 * i]);
    }
}

// ---- per-s mid half (kfft only; verified R10/R12; fences removed) ----
__device__ __forceinline__ void fwd_mid_half(float2 rh[16], float* ldsx, float* ldsy,
                                             const int w, const int l, const int s,
                                             const float2* __restrict__ tw) {
#pragma unroll
    for (int jj = 0; jj < 16; ++jj) {
        const int a = w * RW + PAD(1024 * s + 64 * jj + l);
        rh[jj].x = ldsx[a]; rh[jj].y = ldsy[a];
    }
#pragma unroll
    for (int j0 = 0; j0 < 4; ++j0) {
        const int i1 = 1024 * j0 + 16 * l;
        bfly4(rh[j0], rh[j0 + 4], rh[j0 + 8], rh[j0 + 12], tw[i1], tw[2 * i1], tw[3 * i1]);
    }
    {
        const int i2 = 64 * l;
        const float2 w1 = tw[i2], w2 = tw[2 * i2], w3 = tw[3 * i2];
#pragma unroll
        for (int g = 0; g < 4; ++g)
            bfly4(rh[4 * g], rh[4 * g + 1], rh[4 * g + 2], rh[4 * g + 3], w1, w2, w3);
    }
#pragma unroll
    for (int jj = 0; jj < 16; ++jj) {
        const int a = w * RW + PAD(1024 * s + 64 * jj + l);
        ldsx[a] = rh[jj].x; ldsy[a] = rh[jj].y;
    }
    {
        const int lo = 64 * (l >> 2) + (l & 3);
#pragma unroll
        for (int jj = 0; jj < 16; ++jj) {
            const int a = w * RW + PAD(1024 * s + lo + 4 * jj);
            rh[jj].x = ldsx[a]; rh[jj].y = ldsy[a];
        }
    }
#pragma unroll
    for (int j0 = 0; j0 < 4; ++j0) {
        const int i3 = 1024 * j0 + 256 * (l & 3);
        bfly4(rh[j0], rh[j0 + 4], rh[j0 + 8], rh[j0 + 12], tw[i3], tw[2 * i3], tw[3 * i3]);
    }
    {
        const int i4 = 1024 * (l & 3);
        const float2 w1 = tw[i4], w2 = tw[2 * i4], w3 = tw[3 * i4];
#pragma unroll
        for (int g = 0; g < 4; ++g)
            bfly4(rh[4 * g], rh[4 * g + 1], rh[4 * g + 2], rh[4 * g + 3], w1, w2, w3);
    }
    {
        const int lo = 64 * (l >> 2) + (l & 3);
#pragma unroll
        for (int jj = 0; jj < 16; ++jj) {
            const int a = w * RW + PAD(1024 * s + lo + 4 * jj);
            ldsx[a] = rh[jj].x; ldsy[a] = rh[jj].y;
        }
    }
#pragma unroll
    for (int jj = 0; jj < 16; ++jj) {
        const int a = w * RW + PAD(1024 * s + 16 * l + jj);
        rh[jj].x = ldsx[a]; rh[jj].y = ldsy[a];
    }
#pragma unroll
    for (int g = 0; g < 4; ++g)
        bfly4_nw(rh[4 * g], rh[4 * g + 1], rh[4 * g + 2], rh[4 * g + 3]);
}

// ---- conv fused middle (R11-verified structure; fences removed; Kf pre-scaled) ----
__device__ __forceinline__ void conv_mid_fused(float* ldsx, float* ldsy,
                                               const int t, const int w, const int l,
                                               const float4* __restrict__ kf4,
                                               float tch0, float tch1, float tch2, float tch3,
                                               const float2* __restrict__ tw) {
    float2 r0[16], r1[16];
#pragma unroll
    for (int jj = 0; jj < 16; ++jj) {
        const int a0 = w * RW + PAD(64 * jj + l);
        const int a1 = w * RW + PAD(1024 + 64 * jj + l);
        r0[jj].x = ldsx[a0]; r0[jj].y = ldsy[a0];
        r1[jj].x = ldsx[a1]; r1[jj].y = ldsy[a1];
    }
    // fwd stage q=256
#pragma unroll
    for (int j0 = 0; j0 < 4; ++j0) {
        const int i1 = 1024 * j0 + 16 * l;
        const float2 w1 = tw[i1], w2 = tw[2 * i1], w3 = tw[3 * i1];
        bfly4(r0[j0], r0[j0 + 4], r0[j0 + 8], r0[j0 + 12], w1, w2, w3);
        bfly4(r1[j0], r1[j0 + 4], r1[j0 + 8], r1[j0 + 12], w1, w2, w3);
    }
    // fwd stage q=64 (uniform)
    {
        const int i2 = 64 * l;
        const float2 w1 = tw[i2], w2 = tw[2 * i2], w3 = tw[3 * i2];
#pragma unroll
        for (int g = 0; g < 4; ++g) {
            bfly4(r0[4 * g], r0[4 * g + 1], r0[4 * g + 2], r0[4 * g + 3], w1, w2, w3);
            bfly4(r1[4 * g], r1[4 * g + 1], r1[4 * g + 2], r1[4 * g + 3], w1, w2, w3);
        }
    }
    // W1 -> W2 (compiler-ordered; HW per-wave DS in-order)
#pragma unroll
    for (int jj = 0; jj < 16; ++jj) {
        const int a0 = w * RW + PAD(64 * jj + l);
        const int a1 = w * RW + PAD(1024 + 64 * jj + l);
        ldsx[a0] = r0[jj].x; ldsy[a0] = r0[jj].y;
        ldsx[a1] = r1[jj].x; ldsy[a1] = r1[jj].y;
    }
    {
        const int lo = 64 * (l >> 2) + (l & 3);
#pragma unroll
        for (int jj = 0; jj < 16; ++jj) {
            const int a0 = w * RW + PAD(lo + 4 * jj);
            const int a1 = w * RW + PAD(1024 + lo + 4 * jj);
            r0[jj].x = ldsx[a0]; r0[jj].y = ldsy[a0];
            r1[jj].x = ldsx[a1]; r1[jj].y = ldsy[a1];
        }
    }
    // fwd stage q=16
#pragma unroll
    for (int j0 = 0; j0 < 4; ++j0) {
        const int i3 = 1024 * j0 + 256 * (l & 3);
        const float2 w1 = tw[i3], w2 = tw[2 * i3], w3 = tw[3 * i3];
        bfly4(r0[j0], r0[j0 + 4], r0[j0 + 8], r0[j0 + 12], w1, w2, w3);
        bfly4(r1[j0], r1[j0 + 4], r1[j0 + 8], r1[j0 + 12], w1, w2, w3);
    }
    // fwd stage q=4 (uniform)
    {
        const int i4 = 1024 * (l & 3);
        const float2 w1 = tw[i4], w2 = tw[2 * i4], w3 = tw[3 * i4];
#pragma unroll
        for (int g = 0; g < 4; ++g) {
            bfly4(r0[4 * g], r0[4 * g + 1], r0[4 * g + 2], r0[4 * g + 3], w1, w2, w3);
            bfly4(r1[4 * g], r1[4 * g + 1], r1[4 * g + 2], r1[4 * g + 3], w1, w2, w3);
        }
    }
    // W2 -> W3
    {
        const int lo = 64 * (l >> 2) + (l & 3);
#pragma unroll
        for (int jj = 0; jj < 16; ++jj) {
            const int a0 = w * RW + PAD(lo + 4 * jj);
            const int a1 = w * RW + PAD(1024 + lo + 4 * jj);
            ldsx[a0] = r0[jj].x; ldsy[a0] = r0[jj].y;
            ldsx[a1] = r1[jj].x; ldsy[a1] = r1[jj].y;
        }
    }
#pragma unroll
    for (int jj = 0; jj < 16; ++jj) {
        const int a0 = w * RW + PAD(16 * l + jj);
        const int a1 = w * RW + PAD(1024 + 16 * l + jj);
        r0[jj].x = ldsx[a0]; r0[jj].y = ldsy[a0];
        r1[jj].x = ldsx[a1]; r1[jj].y = ldsy[a1];
    }
    // fwd stage q=1
#pragma unroll
    for (int g = 0; g < 4; ++g) {
        bfly4_nw(r0[4 * g], r0[4 * g + 1], r0[4 * g + 2], r0[4 * g + 3]);
        bfly4_nw(r1[4 * g], r1[4 * g + 1], r1[4 * g + 2], r1[4 * g + 3]);
    }
    // keep L2-prefetch touches alive until here (Kf row is L2-hot now)
    asm volatile("" :: "v"(tch0), "v"(tch1), "v"(tch2), "v"(tch3));
    // pointwise multiply (thread-linear W3 order; Kf PRE-SCALED by 1/N in kfft)
#pragma unroll
    for (int q = 0; q < 8; ++q) {
        const float4 k0 = kf4[16 * t + q];
        const float4 k1 = kf4[16 * t + 8 + q];
        float2 z;
        z = r0[2 * q];
        r0[2 * q]     = make_float2(z.x * k0.x - z.y * k0.y, z.x * k0.y + z.y * k0.x);
        z = r0[2 * q + 1];
        r0[2 * q + 1] = make_float2(z.x * k0.z - z.y * k0.w, z.x * k0.w + z.y * k0.z);
        z = r1[2 * q];
        r1[2 * q]     = make_float2(z.x * k1.x - z.y * k1.y, z.x * k1.y + z.y * k1.x);
        z = r1[2 * q + 1];
        r1[2 * q + 1] = make_float2(z.x * k1.z - z.y * k1.w, z.x * k1.w + z.y * k1.z);
    }
    // inv stage q=1
#pragma unroll
    for (int g = 0; g < 4; ++g) {
        ibfly4_nw(r0[4 * g], r0[4 * g + 1], r0[4 * g + 2], r0[4 * g + 3]);
        ibfly4_nw(r1[4 * g], r1[4 * g + 1], r1[4 * g + 2], r1[4 * g + 3]);
    }
    // W3 -> W2
#pragma unroll
    for (int jj = 0; jj < 16; ++jj) {
        const int a0 = w * RW + PAD(16 * l + jj);
        const int a1 = w * RW + PAD(1024 + 16 * l + jj);
        ldsx[a0] = r0[jj].x; ldsy[a0] = r0[jj].y;
        ldsx[a1] = r1[jj].x; ldsy[a1] = r1[jj].y;
    }
    {
        const int lo = 64 * (l >> 2) + (l & 3);
#pragma unroll
        for (int jj = 0; jj < 16; ++jj) {
            const int a0 = w * RW + PAD(lo + 4 * jj);
            const int a1 = w * RW + PAD(1024 + lo + 4 * jj);
            r0[jj].x = ldsx[a0]; r0[jj].y = ldsy[a0];
            r1[jj].x = ldsx[a1]; r1[jj].y = ldsy[a1];
        }
    }
    // inv stage q=4 (uniform), then q=16
    {
        const int i4 = 1024 * (l & 3);
        const float2 w1 = tw[i4], w2 = tw[2 * i4];
#pragma unroll
        for (int g = 0; g < 4; ++g) {
            ibfly4(r0[4 * g], r0[4 * g + 1], r0[4 * g + 2], r0[4 * g + 3], w1, w2);
            ibfly4(r1[4 * g], r1[4 * g + 1], r1[4 * g + 2], r1[4 * g + 3], w1, w2);
        }
    }
#pragma unroll
    for (int j0 = 0; j0 < 4; ++j0) {
        const int i3 = 1024 * j0 + 256 * (l & 3);
        const float2 w1 = tw[i3], w2 = tw[2 * i3];
        ibfly4(r0[j0], r0[j0 + 4], r0[j0 + 8], r0[j0 + 12], w1, w2);
        ibfly4(r1[j0], r1[j0 + 4], r1[j0 + 8], r1[j0 + 12], w1, w2);
    }
    // W2 -> W1
    {
        const int lo = 64 * (l >> 2) + (l & 3);
#pragma unroll
        for (int jj = 0; jj < 16; ++jj) {
            const int a0 = w * RW + PAD(lo + 4 * jj);
            const int a1 = w * RW + PAD(1024 + lo + 4 * jj);
            ldsx[a0] = r0[jj].x; ldsy[a0] = r0[jj].y;
            ldsx[a1] = r1[jj].x; ldsy[a1] = r1[jj].y;
        }
    }
#pragma unroll
    for (int jj = 0; jj < 16; ++jj) {
        const int a0 = w * RW + PAD(64 * jj + l);
        const int a1 = w * RW + PAD(1024 + 64 * jj + l);
        r0[jj].x = ldsx[a0]; r0[jj].y = ldsy[a0];
        r1[jj].x = ldsx[a1]; r1[jj].y = ldsy[a1];
    }
    // inv stage q=64 (uniform), then q=256
    {
        const int i2 = 64 * l;
        const float2 w1 = tw[i2], w2 = tw[2 * i2];
#pragma unroll
        for (int g = 0; g < 4; ++g) {
            ibfly4(r0[4 * g], r0[4 * g + 1], r0[4 * g + 2], r0[4 * g + 3], w1, w2);
            ibfly4(r1[4 * g], r1[4 * g + 1], r1[4 * g + 2], r1[4 * g + 3], w1, w2);
        }
    }
#pragma unroll
    for (int j0 = 0; j0 < 4; ++j0) {
        const int i1 = 1024 * j0 + 16 * l;
        const float2 w1 = tw[i1], w2 = tw[2 * i1];
        ibfly4(r0[j0], r0[j0 + 4], r0[j0 + 8], r0[j0 + 12], w1, w2);
        ibfly4(r1[j0], r1[j0 + 4], r1[j0 + 8], r1[j0 + 12], w1, w2);
    }
    // write W1 both (caller issues workgroup barrier)
#pragma unroll
    for (int jj = 0; jj < 16; ++jj) {
        const int a0 = w * RW + PAD(64 * jj + l);
        const int a1 = w * RW + PAD(1024 + 64 * jj + l);
        ldsx[a0] = r0[jj].x; ldsy[a0] = r0[jj].y;
        ldsx[a1] = r1[jj].x; ldsy[a1] = r1[jj].y;
    }
}

__device__ __forceinline__ float ftanh(float x) {
    float e = __expf(2.0f * x);
    return 1.0f - 2.0f * __builtin_amdgcn_rcpf(e + 1.0f);
}

__global__ void twiddle_init(float2* __restrict__ tw) {
    int t = blockIdx.x * blockDim.x + threadIdx.x;
    if (t < FFT_N) {
        float ang = -2.0f * 3.14159265358979323846f * (float)t / (float)FFT_N;
        float sv, cv;
        sincosf(ang, &sv, &cv);
        tw[t] = make_float2(cv, sv);
    }
}

// Forward FFT of (k_h + dh*delta) -> Kf[h], thread-linear W3 order, PRE-SCALED
// by 1/N (verified R12).
__global__ __launch_bounds__(NT) void kfft_kernel(const float* __restrict__ k,
                                                  const float* __restrict__ D,
                                                  const float2* __restrict__ tw,
                                                  float2* __restrict__ Kf) {
    __shared__ float ldsx[8 * RW];
    __shared__ float ldsy[8 * RW];
    const int h = blockIdx.x;
    const int t = threadIdx.x;
    const int w = t >> 6, l = t & 63;
    const float* krow = k + (size_t)h * FFT_N;
    const float dh = D[h * (H_DIM + 1)];
#pragma unroll
    for (int par = 0; par < 2; ++par) {
        float2 rh[16];
#pragma unroll
        for (int m = 0; m < 16; ++m)
            rh[m] = make_float2(krow[t + 512 * par + 1024 * m], 0.f);
        if (par == 0 && t == 0) rh[0].x += dh;   // fold diag(D) into k's 0th tap
        fwd_g01_half(rh, t, par, tw);
#pragma unroll
        for (int m = 0; m < 16; ++m) {
            const int e = t + 512 * par + 1024 * m;
            const int a = (e >> 11) * RW + PAD(e & 2047);
            ldsx[a] = rh[m].x; ldsy[a] = rh[m].y;
        }
    }
    __syncthreads();
    const float invN = 1.0f / (float)FFT_N;
    float4* out4 = (float4*)(Kf + (size_t)h * FFT_N);
#pragma unroll
    for (int s = 0; s < 2; ++s) {
        float2 rh[16];
        fwd_mid_half(rh, ldsx, ldsy, w, l, s, tw);
#pragma unroll
        for (int q = 0; q < 8; ++q)
            out4[16 * t + 8 * s + q] =
                make_float4(rh[2 * q].x * invN, rh[2 * q].y * invN,
                            rh[2 * q + 1].x * invN, rh[2 * q + 1].y * invN);
    }
}

// Batch rows (2p,h) and (2p+1,h) packed as z = u0 + i*u1.
__global__ __launch_bounds__(NT) void conv_kernel(const float* __restrict__ u,
                                                  const float2* __restrict__ tw,
                                                  const float2* __restrict__ Kf,
                                                  float* __restrict__ out) {
    __shared__ float ldsx[8 * RW];
    __shared__ float ldsy[8 * RW];
    const int raw = blockIdx.x;
    const int vb = ((raw & 7) << 7) + (raw >> 3);   // XCD-chunked bijection
    const int h = vb >> 2;
    const int p = vb & 3;
    const int t = threadIdx.x;
    const int w = t >> 6, l = t & 63;
    const size_t row0 = ((size_t)(2 * p) * H_DIM + h) * FFT_N;
    const size_t row1 = row0 + (size_t)H_DIM * FFT_N;
    const float* u0 = u + row0;
    const float* u1 = u + row1;

    // L2-prefetch touches for the Kf row (2048 x 64B lines, 4/thread), issued
    // now, sunk just before the pointwise step inside the middle.
    const float* kfw = (const float*)(Kf + (size_t)h * FFT_N);
    const float tch0 = kfw[16 * t];
    const float tch1 = kfw[16 * (t + 512)];
    const float tch2 = kfw[16 * (t + 1024)];
    const float tch3 = kfw[16 * (t + 1536)];

    // entry: two independent 16-register half-passes (verified R10..R12)
#pragma unroll
    for (int par = 0; par < 2; ++par) {
        float2 rh[16];
#pragma unroll
        for (int m = 0; m < 16; ++m) {
            const int n = t + 512 * par + 1024 * m;
            rh[m] = make_float2(u0[n], u1[n]);
        }
        fwd_g01_half(rh, t, par, tw);
#pragma unroll
        for (int m = 0; m < 16; ++m) {
            const int e = t + 512 * par + 1024 * m;
            const int a = (e >> 11) * RW + PAD(e & 2047);
            ldsx[a] = rh[m].x; ldsy[a] = rh[m].y;
        }
    }
    __syncthreads();

    // fused full-width middle (fwd + pointwise + inv), no explicit fences
    conv_mid_fused(ldsx, ldsy, t, w, l,
                   (const float4*)(Kf + (size_t)h * FFT_N),
                   tch0, tch1, tch2, tch3, tw);
    __syncthreads();

    // exit: per-parity half-passes
    float* o0 = out + row0;
    float* o1 = out + row1;
#pragma unroll
    for (int par = 0; par < 2; ++par) {
        float2 rh[16];
#pragma unroll
        for (int m = 0; m < 16; ++m) {
            const int e = t + 512 * par + 1024 * m;
            const int a = (e >> 11) * RW + PAD(e & 2047);
            rh[m].x = ldsx[a]; rh[m].y = ldsy[a];
        }
        inv_g01_half(rh, t, par, tw);
#pragma unroll
        for (int m = 0; m < 16; ++m) {
            const int n = t + 512 * par + 1024 * m;
            o0[n] = ftanh(rh[m].x);
            o1[n] = ftanh(rh[m].y);
        }
    }
}

extern "C" void kernel_launch(void* const* d_in, const int* in_sizes, int n_in,
                              void* d_out, int out_size, void* d_ws, size_t ws_size,
                              hipStream_t stream) {
    const float* u = (const float*)d_in[0];   // (B,H,L) f32
    const float* k = (const float*)d_in[1];   // (H,L)   f32
    const float* D = (const float*)d_in[2];   // (H,H)   f32
    float* out = (float*)d_out;

    float2* tw = (float2*)d_ws;               // 16384 float2 = 128 KiB
    float2* Kf = tw + FFT_N;                  // 256*16384 float2 = 32 MiB

    twiddle_init<<<FFT_N / 256, 256, 0, stream>>>(tw);
    kfft_kernel<<<H_DIM, NT, 0, stream>>>(k, D, tw, Kf);
    conv_kernel<<<(B_DIM / 2) * H_DIM, NT, 0, stream>>>(u, tw, Kf, out);
}

// Round 14
// 193.868 us; speedup vs baseline: 1.1140x; 1.0820x over previous
//
#include <hip/hip_runtime.h>
#include <math.h>

#define FFT_N 16384
#define NT 512
#define B_DIM 8
#define H_DIM 256

// Single float2 plane (128 KiB), b64 DS ops. XOR swizzle in float2-index
// space: bijective, keeps each wave's 2048-element region closed, and holds
// every access map at <=4 lanes per bank-pair (= b64 wave capacity):
//   nA (t+512j), W1 (64jj+l), W2 (64(l>>2)+4jj+(l&3)), W3 (16l+jj)  [hand-checked]
#define SWZ2(a) ((a) ^ (((a) >> 5) & 15) ^ (((a) >> 9) & 1))

// No wave-local fences: per-wave DS in-order + compiler alias ordering,
// HW-validated in R13 (absmax bit-identical). Cross-wave points keep
// __syncthreads.

__device__ __forceinline__ float2 cmul(float2 a, float2 b) {
    return make_float2(a.x * b.x - a.y * b.y, a.x * b.y + a.y * b.x);
}
__device__ __forceinline__ float2 cadd(float2 a, float2 b) { return make_float2(a.x + b.x, a.y + b.y); }
__device__ __forceinline__ float2 csub(float2 a, float2 b) { return make_float2(a.x - b.x, a.y - b.y); }
__device__ __forceinline__ float2 mulnegi(float2 z) { return make_float2(z.y, -z.x); }   // -i*z
__device__ __forceinline__ float2 mulposi(float2 z) { return make_float2(-z.y, z.x); }   // +i*z

// ---- radix-4 butterflies (verified R1..R13) ----
__device__ __forceinline__ void bfly4(float2& a, float2& b, float2& c, float2& d,
                                      float2 w1, float2 w2, float2 w3) {
    float2 apc = cadd(a, c), amc = csub(a, c);
    float2 bpd = cadd(b, d), bmd = csub(b, d);
    float2 nib = mulnegi(bmd);
    a = cadd(apc, bpd);
    b = cmul(csub(apc, bpd), w2);
    c = cmul(cadd(amc, nib), w1);
    d = cmul(csub(amc, nib), w3);
}
__device__ __forceinline__ void bfly4_nw(float2& a, float2& b, float2& c, float2& d) {
    float2 apc = cadd(a, c), amc = csub(a, c);
    float2 bpd = cadd(b, d), bmd = csub(b, d);
    float2 nib = mulnegi(bmd);
    a = cadd(apc, bpd);
    b = csub(apc, bpd);
    c = cadd(amc, nib);
    d = csub(amc, nib);
}
__device__ __forceinline__ void ibfly4(float2& a, float2& b, float2& c, float2& d,
                                       float2 w1t, float2 w2t) {
    float2 w1 = make_float2(w1t.x, -w1t.y);
    float2 w2 = make_float2(w2t.x, -w2t.y);
    float2 bt = cmul(b, w2), dt = cmul(d, w2);
    float2 A = cadd(a, bt), Bb = csub(a, bt);
    float2 C = cadd(c, dt), Dd = csub(c, dt);
    float2 Cw = cmul(C, w1);
    float2 Dw = mulposi(cmul(Dd, w1));
    a = cadd(A, Cw);  c = csub(A, Cw);
    b = cadd(Bb, Dw); d = csub(Bb, Dw);
}
__device__ __forceinline__ void ibfly4_nw(float2& a, float2& b, float2& c, float2& d) {
    float2 A = cadd(a, b), Bb = csub(a, b);
    float2 C = cadd(c, d), Dd = csub(c, d);
    float2 Dw = mulposi(Dd);
    a = cadd(A, C);  c = csub(A, C);
    b = cadd(Bb, Dw); d = csub(Bb, Dw);
}

// ---- g01 half-passes (verified R10..R13) ----
__device__ __forceinline__ void fwd_g01_half(float2 rh[16], const int t, const int par,
                                             const float2* __restrict__ tw) {
#pragma unroll
    for (int m0 = 0; m0 < 4; ++m0) {
        const int i = t + 512 * par + 1024 * m0;
        bfly4(rh[m0], rh[m0 + 4], rh[m0 + 8], rh[m0 + 12], tw[i], tw[2 * i], tw[3 * i]);
    }
    {
        const int ig = (t + 512 * par) * 4;
        const float2 w1 = tw[ig], w2 = tw[2 * ig], w3 = tw[3 * ig];
#pragma unroll
        for (int a = 0; a < 4; ++a)
            bfly4(rh[4 * a], rh[4 * a + 1], rh[4 * a + 2], rh[4 * a + 3], w1, w2, w3);
    }
}
__device__ __forceinline__ void inv_g01_half(float2 rh[16], const int t, const int par,
                                             const float2* __restrict__ tw) {
    {
        const int ig = (t + 512 * par) * 4;
        const float2 w1 = tw[ig], w2 = tw[2 * ig];
#pragma unroll
        for (int a = 0; a < 4; ++a)
            ibfly4(rh[4 * a], rh[4 * a + 1], rh[4 * a + 2], rh[4 * a + 3], w1, w2);
    }
#pragma unroll
    for (int m0 = 0; m0 < 4; ++m0) {
        const int i = t + 512 * par + 1024 * m0;
        ibfly4(rh[m0], rh[m0 + 4], rh[m0 + 8], rh[m0 + 12], tw[i], tw[2 * i]);
    }
}

// ---- per-s mid half (kfft only; R10/R13 structure on the float2 plane) ----
__device__ __forceinline__ void fwd_mid_half(float2 rh[16], float2* lds2,
                                             const int w, const int l, const int s,
                                             const float2* __restrict__ tw) {
    const int base = w * 2048 + 1024 * s;
#pragma unroll
    for (int jj = 0; jj < 16; ++jj)
        rh[jj] = lds2[SWZ2(base + 64 * jj + l)];
#pragma unroll
    for (int j0 = 0; j0 < 4; ++j0) {
        const int i1 = 1024 * j0 + 16 * l;
        bfly4(rh[j0], rh[j0 + 4], rh[j0 + 8], rh[j0 + 12], tw[i1], tw[2 * i1], tw[3 * i1]);
    }
    {
        const int i2 = 64 * l;
        const float2 w1 = tw[i2], w2 = tw[2 * i2], w3 = tw[3 * i2];
#pragma unroll
        for (int g = 0; g < 4; ++g)
            bfly4(rh[4 * g], rh[4 * g + 1], rh[4 * g + 2], rh[4 * g + 3], w1, w2, w3);
    }
#pragma unroll
    for (int jj = 0; jj < 16; ++jj)
        lds2[SWZ2(base + 64 * jj + l)] = rh[jj];
    {
        const int lo = 64 * (l >> 2) + (l & 3);
#pragma unroll
        for (int jj = 0; jj < 16; ++jj)
            rh[jj] = lds2[SWZ2(base + lo + 4 * jj)];
    }
#pragma unroll
    for (int j0 = 0; j0 < 4; ++j0) {
        const int i3 = 1024 * j0 + 256 * (l & 3);
        bfly4(rh[j0], rh[j0 + 4], rh[j0 + 8], rh[j0 + 12], tw[i3], tw[2 * i3], tw[3 * i3]);
    }
    {
        const int i4 = 1024 * (l & 3);
        const float2 w1 = tw[i4], w2 = tw[2 * i4], w3 = tw[3 * i4];
#pragma unroll
        for (int g = 0; g < 4; ++g)
            bfly4(rh[4 * g], rh[4 * g + 1], rh[4 * g + 2], rh[4 * g + 3], w1, w2, w3);
    }
    {
        const int lo = 64 * (l >> 2) + (l & 3);
#pragma unroll
        for (int jj = 0; jj < 16; ++jj)
            lds2[SWZ2(base + lo + 4 * jj)] = rh[jj];
    }
#pragma unroll
    for (int jj = 0; jj < 16; ++jj)
        rh[jj] = lds2[SWZ2(base + 16 * l + jj)];
#pragma unroll
    for (int g = 0; g < 4; ++g)
        bfly4_nw(rh[4 * g], rh[4 * g + 1], rh[4 * g + 2], rh[4 * g + 3]);
}

// ---- conv fused middle (R11 champion structure; float2/b64 plane; Kf pre-scaled) ----
__device__ __forceinline__ void conv_mid_fused(float2* lds2,
                                               const int t, const int w, const int l,
                                               const float4* __restrict__ kf4,
                                               const float2* __restrict__ tw) {
    const int base = w * 2048;
    const int lo = 64 * (l >> 2) + (l & 3);
    float2 r0[16], r1[16];
#pragma unroll
    for (int jj = 0; jj < 16; ++jj) {
        r0[jj] = lds2[SWZ2(base + 64 * jj + l)];
        r1[jj] = lds2[SWZ2(base + 1024 + 64 * jj + l)];
    }
    // fwd stage q=256
#pragma unroll
    for (int j0 = 0; j0 < 4; ++j0) {
        const int i1 = 1024 * j0 + 16 * l;
        const float2 w1 = tw[i1], w2 = tw[2 * i1], w3 = tw[3 * i1];
        bfly4(r0[j0], r0[j0 + 4], r0[j0 + 8], r0[j0 + 12], w1, w2, w3);
        bfly4(r1[j0], r1[j0 + 4], r1[j0 + 8], r1[j0 + 12], w1, w2, w3);
    }
    // fwd stage q=64 (uniform)
    {
        const int i2 = 64 * l;
        const float2 w1 = tw[i2], w2 = tw[2 * i2], w3 = tw[3 * i2];
#pragma unroll
        for (int g = 0; g < 4; ++g) {
            bfly4(r0[4 * g], r0[4 * g + 1], r0[4 * g + 2], r0[4 * g + 3], w1, w2, w3);
            bfly4(r1[4 * g], r1[4 * g + 1], r1[4 * g + 2], r1[4 * g + 3], w1, w2, w3);
        }
    }
    // W1 -> W2
#pragma unroll
    for (int jj = 0; jj < 16; ++jj) {
        lds2[SWZ2(base + 64 * jj + l)] = r0[jj];
        lds2[SWZ2(base + 1024 + 64 * jj + l)] = r1[jj];
    }
#pragma unroll
    for (int jj = 0; jj < 16; ++jj) {
        r0[jj] = lds2[SWZ2(base + lo + 4 * jj)];
        r1[jj] = lds2[SWZ2(base + 1024 + lo + 4 * jj)];
    }
    // fwd stage q=16
#pragma unroll
    for (int j0 = 0; j0 < 4; ++j0) {
        const int i3 = 1024 * j0 + 256 * (l & 3);
        const float2 w1 = tw[i3], w2 = tw[2 * i3], w3 = tw[3 * i3];
        bfly4(r0[j0], r0[j0 + 4], r0[j0 + 8], r0[j0 + 12], w1, w2, w3);
        bfly4(r1[j0], r1[j0 + 4], r1[j0 + 8], r1[j0 + 12], w1, w2, w3);
    }
    // fwd stage q=4 (uniform)
    {
        const int i4 = 1024 * (l & 3);
        const float2 w1 = tw[i4], w2 = tw[2 * i4], w3 = tw[3 * i4];
#pragma unroll
        for (int g = 0; g < 4; ++g) {
            bfly4(r0[4 * g], r0[4 * g + 1], r0[4 * g + 2], r0[4 * g + 3], w1, w2, w3);
            bfly4(r1[4 * g], r1[4 * g + 1], r1[4 * g + 2], r1[4 * g + 3], w1, w2, w3);
        }
    }
    // W2 -> W3
#pragma unroll
    for (int jj = 0; jj < 16; ++jj) {
        lds2[SWZ2(base + lo + 4 * jj)] = r0[jj];
        lds2[SWZ2(base + 1024 + lo + 4 * jj)] = r1[jj];
    }
#pragma unroll
    for (int jj = 0; jj < 16; ++jj) {
        r0[jj] = lds2[SWZ2(base + 16 * l + jj)];
        r1[jj] = lds2[SWZ2(base + 1024 + 16 * l + jj)];
    }
    // fwd stage q=1
#pragma unroll
    for (int g = 0; g < 4; ++g) {
        bfly4_nw(r0[4 * g], r0[4 * g + 1], r0[4 * g + 2], r0[4 * g + 3]);
        bfly4_nw(r1[4 * g], r1[4 * g + 1], r1[4 * g + 2], r1[4 * g + 3]);
    }
    // pointwise multiply (thread-linear W3 order; Kf PRE-SCALED by 1/N)
#pragma unroll
    for (int q = 0; q < 8; ++q) {
        const float4 k0 = kf4[16 * t + q];
        const float4 k1 = kf4[16 * t + 8 + q];
        float2 z;
        z = r0[2 * q];
        r0[2 * q]     = make_float2(z.x * k0.x - z.y * k0.y, z.x * k0.y + z.y * k0.x);
        z = r0[2 * q + 1];
        r0[2 * q + 1] = make_float2(z.x * k0.z - z.y * k0.w, z.x * k0.w + z.y * k0.z);
        z = r1[2 * q];
        r1[2 * q]     = make_float2(z.x * k1.x - z.y * k1.y, z.x * k1.y + z.y * k1.x);
        z = r1[2 * q + 1];
        r1[2 * q + 1] = make_float2(z.x * k1.z - z.y * k1.w, z.x * k1.w + z.y * k1.z);
    }
    // inv stage q=1
#pragma unroll
    for (int g = 0; g < 4; ++g) {
        ibfly4_nw(r0[4 * g], r0[4 * g + 1], r0[4 * g + 2], r0[4 * g + 3]);
        ibfly4_nw(r1[4 * g], r1[4 * g + 1], r1[4 * g + 2], r1[4 * g + 3]);
    }
    // W3 -> W2
#pragma unroll
    for (int jj = 0; jj < 16; ++jj) {
        lds2[SWZ2(base + 16 * l + jj)] = r0[jj];
        lds2[SWZ2(base + 1024 + 16 * l + jj)] = r1[jj];
    }
#pragma unroll
    for (int jj = 0; jj < 16; ++jj) {
        r0[jj] = lds2[SWZ2(base + lo + 4 * jj)];
        r1[jj] = lds2[SWZ2(base + 1024 + lo + 4 * jj)];
    }
    // inv stage q=4 (uniform), then q=16
    {
        const int i4 = 1024 * (l & 3);
        const float2 w1 = tw[i4], w2 = tw[2 * i4];
#pragma unroll
        for (int g = 0; g < 4; ++g) {
            ibfly4(r0[4 * g], r0[4 * g + 1], r0[4 * g + 2], r0[4 * g + 3], w1, w2);
            ibfly4(r1[4 * g], r1[4 * g + 1], r1[4 * g + 2], r1[4 * g + 3], w1, w2);
        }
    }
#pragma unroll
    for (int j0 = 0; j0 < 4; ++j0) {
        const int i3 = 1024 * j0 + 256 * (l & 3);
        const float2 w1 = tw[i3], w2 = tw[2 * i3];
        ibfly4(r0[j0], r0[j0 + 4], r0[j0 + 8], r0[j0 + 12], w1, w2);
        ibfly4(r1[j0], r1[j0 + 4], r1[j0 + 8], r1[j0 + 12], w1, w2);
    }
    // W2 -> W1
#pragma unroll
    for (int jj = 0; jj < 16; ++jj) {
        lds2[SWZ2(base + lo + 4 * jj)] = r0[jj];
        lds2[SWZ2(base + 1024 + lo + 4 * jj)] = r1[jj];
    }
#pragma unroll
    for (int jj = 0; jj < 16; ++jj) {
        r0[jj] = lds2[SWZ2(base + 64 * jj + l)];
        r1[jj] = lds2[SWZ2(base + 1024 + 64 * jj + l)];
    }
    // inv stage q=64 (uniform), then q=256
    {
        const int i2 = 64 * l;
        const float2 w1 = tw[i2], w2 = tw[2 * i2];
#pragma unroll
        for (int g = 0; g < 4; ++g) {
            ibfly4(r0[4 * g], r0[4 * g + 1], r0[4 * g + 2], r0[4 * g + 3], w1, w2);
            ibfly4(r1[4 * g], r1[4 * g + 1], r1[4 * g + 2], r1[4 * g + 3], w1, w2);
        }
    }
#pragma unroll
    for (int j0 = 0; j0 < 4; ++j0) {
        const int i1 = 1024 * j0 + 16 * l;
        const float2 w1 = tw[i1], w2 = tw[2 * i1];
        ibfly4(r0[j0], r0[j0 + 4], r0[j0 + 8], r0[j0 + 12], w1, w2);
        ibfly4(r1[j0], r1[j0 + 4], r1[j0 + 8], r1[j0 + 12], w1, w2);
    }
    // write W1 both (caller issues workgroup barrier)
#pragma unroll
    for (int jj = 0; jj < 16; ++jj) {
        lds2[SWZ2(base + 64 * jj + l)] = r0[jj];
        lds2[SWZ2(base + 1024 + 64 * jj + l)] = r1[jj];
    }
}

__device__ __forceinline__ float ftanh(float x) {
    float e = __expf(2.0f * x);
    return 1.0f - 2.0f * __builtin_amdgcn_rcpf(e + 1.0f);
}

__global__ void twiddle_init(float2* __restrict__ tw) {
    int t = blockIdx.x * blockDim.x + threadIdx.x;
    if (t < FFT_N) {
        float ang = -2.0f * 3.14159265358979323846f * (float)t / (float)FFT_N;
        float sv, cv;
        sincosf(ang, &sv, &cv);
        tw[t] = make_float2(cv, sv);
    }
}

// Forward FFT of (k_h + dh*delta) -> Kf[h], thread-linear W3 order,
// PRE-SCALED by 1/N (verified R12/R13).
__global__ __launch_bounds__(NT) void kfft_kernel(const float* __restrict__ k,
                                                  const float* __restrict__ D,
                                                  const float2* __restrict__ tw,
                                                  float2* __restrict__ Kf) {
    __shared__ float2 lds2[FFT_N];   // 131072 B
    const int h = blockIdx.x;
    const int t = threadIdx.x;
    const int w = t >> 6, l = t & 63;
    const float* krow = k + (size_t)h * FFT_N;
    const float dh = D[h * (H_DIM + 1)];
#pragma unroll
    for (int par = 0; par < 2; ++par) {
        float2 rh[16];
#pragma unroll
        for (int m = 0; m < 16; ++m)
            rh[m] = make_float2(krow[t + 512 * par + 1024 * m], 0.f);
        if (par == 0 && t == 0) rh[0].x += dh;   // fold diag(D) into k's 0th tap
        fwd_g01_half(rh, t, par, tw);
#pragma unroll
        for (int m = 0; m < 16; ++m) {
            const int e = t + 512 * par + 1024 * m;
            lds2[SWZ2(e)] = rh[m];
        }
    }
    __syncthreads();
    const float invN = 1.0f / (float)FFT_N;
    float4* out4 = (float4*)(Kf + (size_t)h * FFT_N);
#pragma unroll
    for (int s = 0; s < 2; ++s) {
        float2 rh[16];
        fwd_mid_half(rh, lds2, w, l, s, tw);
#pragma unroll
        for (int q = 0; q < 8; ++q)
            out4[16 * t + 8 * s + q] =
                make_float4(rh[2 * q].x * invN, rh[2 * q].y * invN,
                            rh[2 * q + 1].x * invN, rh[2 * q + 1].y * invN);
    }
}

// Batch rows (2p,h) and (2p+1,h) packed as z = u0 + i*u1.
__global__ __launch_bounds__(NT) void conv_kernel(const float* __restrict__ u,
                                                  const float2* __restrict__ tw,
                                                  const float2* __restrict__ Kf,
                                                  float* __restrict__ out) {
    __shared__ float2 lds2[FFT_N];   // 131072 B
    const int raw = blockIdx.x;
    const int vb = ((raw & 7) << 7) + (raw >> 3);   // XCD-chunked bijection
    const int h = vb >> 2;
    const int p = vb & 3;
    const int t = threadIdx.x;
    const int w = t >> 6, l = t & 63;
    const size_t row0 = ((size_t)(2 * p) * H_DIM + h) * FFT_N;
    const size_t row1 = row0 + (size_t)H_DIM * FFT_N;
    const float* u0 = u + row0;
    const float* u1 = u + row1;

    // entry: two independent 16-register half-passes (verified R10..R13)
#pragma unroll
    for (int par = 0; par < 2; ++par) {
        float2 rh[16];
#pragma unroll
        for (int m = 0; m < 16; ++m) {
            const int n = t + 512 * par + 1024 * m;
            rh[m] = make_float2(u0[n], u1[n]);
        }
        fwd_g01_half(rh, t, par, tw);
#pragma unroll
        for (int m = 0; m < 16; ++m) {
            const int e = t + 512 * par + 1024 * m;
            lds2[SWZ2(e)] = rh[m];
        }
    }
    __syncthreads();

    // fused full-width middle (fwd + pointwise + inv)
    conv_mid_fused(lds2, t, w, l, (const float4*)(Kf + (size_t)h * FFT_N), tw);
    __syncthreads();

    // exit: per-parity half-passes
    float* o0 = out + row0;
    float* o1 = out + row1;
#pragma unroll
    for (int par = 0; par < 2; ++par) {
        float2 rh[16];
#pragma unroll
        for (int m = 0; m < 16; ++m) {
            const int e = t + 512 * par + 1024 * m;
            rh[m] = lds2[SWZ2(e)];
        }
        inv_g01_half(rh, t, par, tw);
#pragma unroll
        for (int m = 0; m < 16; ++m) {
            const int n = t + 512 * par + 1024 * m;
            o0[n] = ftanh(rh[m].x);
            o1[n] = ftanh(rh[m].y);
        }
    }
}

extern "C" void kernel_launch(void* const* d_in, const int* in_sizes, int n_in,
                              void* d_out, int out_size, void* d_ws, size_t ws_size,
                              hipStream_t stream) {
    const float* u = (const float*)d_in[0];   // (B,H,L) f32
    const float* k = (const float*)d_in[1];   // (H,L)   f32
    const float* D = (const float*)d_in[2];   // (H,H)   f32
    float* out = (float*)d_out;

    float2* tw = (float2*)d_ws;               // 16384 float2 = 128 KiB
    float2* Kf = tw + FFT_N;                  // 256*16384 float2 = 32 MiB

    twiddle_init<<<FFT_N / 256, 256, 0, stream>>>(tw);
    kfft_kernel<<<H_DIM, NT, 0, stream>>>(k, D, tw, Kf);
    conv_kernel<<<(B_DIM / 2) * H_DIM, NT, 0, stream>>>(u, tw, Kf, out);
}